// Round 1
// baseline (132.939 us; speedup 1.0000x reference)
//
#include <hip/hip_runtime.h>
#include <math.h>

// Canny-style Sobel NMS + double threshold on 4096x4096 f32.
// Reference's direction predicate b1 is vacuously true (radians vs degree
// thresholds), so NMS always compares horizontal neighbors -> no atan2 needed.

constexpr int Wd = 4096;
constexpr int Ht = 4096;
constexpr int TW = 64;        // tile width  (output cols per block)
constexpr int TH = 32;        // tile height (output rows per block)
constexpr int LW = TW + 4;    // staged cols: c0-2 .. c0+TW+1  (68)
constexpr int LH = TH + 2;    // staged rows: r0-1 .. r0+TH    (34)
constexpr int LS = 73;        // LDS row stride; 73%32=9 -> 2-way bank aliasing (free)

__global__ __launch_bounds__(256) void canny_kernel(const float* __restrict__ x,
                                                    float* __restrict__ out) {
    __shared__ float xs[LH * LS];
    const int tid = threadIdx.x;
    const int c0 = blockIdx.x * TW;
    const int r0 = blockIdx.y * TH;

    // ---- Stage input window (zero-padded at image borders) ----
    #pragma unroll
    for (int k = 0; k < (LH * LW + 255) / 256; ++k) {
        int i = tid + k * 256;
        if (i < LH * LW) {
            int lr = i / LW;
            int lc = i - lr * LW;
            int r = r0 - 1 + lr;
            int c = c0 - 2 + lc;
            float v = 0.0f;
            if ((unsigned)r < (unsigned)Ht && (unsigned)c < (unsigned)Wd)
                v = x[(size_t)r * Wd + c];
            xs[lr * LS + lc] = v;
        }
    }
    __syncthreads();

    // ---- Each thread: one output row, 8 consecutive output cols ----
    const int rl  = tid >> 3;      // 0..31 local row
    const int seg = tid & 7;       // 0..7  column segment
    const int r   = r0 + rl;       // global output row
    const int p0  = seg * 8;       // tile-local starting col

    const float* __restrict__ ra = &xs[rl * LS];   // global row r-1
    const float* __restrict__ rb = ra + LS;        // global row r
    const float* __restrict__ rc = rb + LS;        // global row r+1

    // t at tile-local col q lives at LDS col q+2.
    // t1 = vertical smooth (for gx), t2 = vertical diff (for gy).
    auto T = [&](int q, float& t1, float& t2) {
        float a = ra[q + 2];
        float b = rb[q + 2];
        float c = rc[q + 2];
        t1 = a + 2.0f * b + c;
        t2 = a - c;
    };
    // mag(q) from t(q-1), t(q), t(q+1)
    auto MAG = [](float t1l, float t2l, float t2m, float t1r, float t2r) {
        float gx = t1r - t1l;
        float gy = t2l + 2.0f * t2m + t2r;
        return sqrtf(gx * gx + gy * gy);
    };

    float t1m, t2m, t1a, t2a, t1b, t2b, t1c, t2c;
    T(p0 - 2, t1m, t2m);   // t(p0-2)
    T(p0 - 1, t1a, t2a);   // t(p0-1)
    T(p0,     t1b, t2b);   // t(p0)
    T(p0 + 1, t1c, t2c);   // t(p0+1)

    float m_prev = MAG(t1m, t2m, t2a, t1b, t2b);   // mag(p0-1)
    float m_cur  = MAG(t1a, t2a, t2b, t1c, t2c);   // mag(p0)

    float acc[8];
    #pragma unroll
    for (int s = 0; s < 8; ++s) {
        float t1n, t2n;
        T(p0 + s + 2, t1n, t2n);                       // t(p+2)
        float m_next = MAG(t1b, t2b, t2c, t1n, t2n);   // mag(p+1)
        bool keep = (m_cur >= m_prev) && (m_cur >= m_next);
        float e = keep ? m_cur : 0.0f;
        // strong -> 255; weak [0.05,0.15] -> 0; below-low passes through
        float v = (e > 0.15f) ? 255.0f : ((e >= 0.05f) ? 0.0f : e);
        acc[s] = v;
        m_prev = m_cur; m_cur = m_next;
        t1b = t1c; t2b = t2c; t1c = t1n; t2c = t2n;
    }

    // Border shell of the output is exactly zero in the reference.
    if (r == 0 || r == Ht - 1) {
        #pragma unroll
        for (int s = 0; s < 8; ++s) acc[s] = 0.0f;
    }
    const int cbase = c0 + p0;
    if (cbase == 0)            acc[0] = 0.0f;
    if (cbase + 7 == Wd - 1)   acc[7] = 0.0f;

    float4* o4 = reinterpret_cast<float4*>(out + (size_t)r * Wd + cbase);
    o4[0] = make_float4(acc[0], acc[1], acc[2], acc[3]);
    o4[1] = make_float4(acc[4], acc[5], acc[6], acc[7]);
}

extern "C" void kernel_launch(void* const* d_in, const int* in_sizes, int n_in,
                              void* d_out, int out_size, void* d_ws, size_t ws_size,
                              hipStream_t stream) {
    const float* x = (const float*)d_in[0];
    float* out = (float*)d_out;
    dim3 grid(Wd / TW, Ht / TH);
    canny_kernel<<<grid, dim3(256), 0, stream>>>(x, out);
}

// Round 2
// 124.631 us; speedup vs baseline: 1.0667x; 1.0667x over previous
//
#include <hip/hip_runtime.h>
#include <math.h>

// Canny-style Sobel NMS + double threshold on 4096x4096 f32.
// Reference's direction predicate b1 is vacuously true (radians compared to
// degree thresholds), so NMS always compares horizontal neighbors.
//
// R2: all LDS traffic vectorized to b128. Stage [c0-4, c0+72) per row as
// float4 chunks (halo +-4 => every chunk is fully in-bounds or fully OOB);
// each thread reads its 3x16-float window as 12 independent ds_read_b128,
// then computes entirely in registers. LDS row stride = 19 chunks (304 B):
// bank-quad (3*rl + 2*seg + ch) % 8 is uniform over the wave -> conflict-free.

constexpr int Wd = 4096;
constexpr int Ht = 4096;
constexpr int TW = 64;         // output cols per block
constexpr int TH = 32;         // output rows per block
constexpr int LH  = TH + 2;    // staged rows (34)
constexpr int LSC = 19;        // float4 chunks per LDS row (stride 304 B)
constexpr int NCH = LH * LSC;  // 646 chunks total

__global__ __launch_bounds__(256) void canny_kernel(const float* __restrict__ x,
                                                    float* __restrict__ out) {
    __shared__ float4 xs[NCH];   // 10,336 B
    const int tid = threadIdx.x;
    const int c0 = blockIdx.x * TW;
    const int r0 = blockIdx.y * TH;

    // ---- Stage: float4 global loads -> ds_write_b128 ----
    // chunk cc of row lr covers input cols [c0-4+4cc, c0+4cc). With the +-4
    // halo, a chunk is either fully in-bounds or fully out (cols are 4-aligned
    // and the image width is a multiple of 4).
    #pragma unroll
    for (int k = 0; k < 3; ++k) {
        int i = tid + k * 256;
        if (i < NCH) {
            int lr = i / LSC;
            int cc = i - lr * LSC;
            int r = r0 - 1 + lr;
            int c = c0 - 4 + 4 * cc;
            float4 v = make_float4(0.f, 0.f, 0.f, 0.f);
            if ((unsigned)r < (unsigned)Ht && (unsigned)c < (unsigned)Wd)
                v = *reinterpret_cast<const float4*>(x + (size_t)r * Wd + c);
            xs[i] = v;
        }
    }
    __syncthreads();

    // ---- Each thread: one output row, 8 consecutive output cols ----
    const int rl  = tid >> 3;      // 0..31 local row
    const int seg = tid & 7;       // 0..7  column segment
    const int r   = r0 + rl;       // global output row
    const int cbase = c0 + seg * 8;

    // LDS float-col j of this thread's window = input col c0 + seg*8 + j - 4.
    const float4* pa = &xs[rl * LSC + seg * 2];   // global row r-1
    const float4* pb = pa + LSC;                  // global row r
    const float4* pc = pa + 2 * LSC;              // global row r+1

    // 12 independent ds_read_b128, one lgkm drain.
    float ar[16], br[16], cr[16];
    #pragma unroll
    for (int k = 0; k < 4; ++k) {
        *reinterpret_cast<float4*>(&ar[4 * k]) = pa[k];
        *reinterpret_cast<float4*>(&br[4 * k]) = pb[k];
        *reinterpret_cast<float4*>(&cr[4 * k]) = pc[k];
    }

    // Vertical pass: t1 = smooth (for gx), t2 = diff (for gy). Needed j: 2..13.
    float t1[16], t2[16];
    #pragma unroll
    for (int j = 2; j < 14; ++j) {
        t1[j] = ar[j] + 2.0f * br[j] + cr[j];
        t2[j] = ar[j] - cr[j];
    }

    // m[s] = gradient magnitude at output col cbase + s - 1  (s = 0..9).
    float m[10];
    #pragma unroll
    for (int s = 0; s < 10; ++s) {
        int j = s + 3;
        float gx = t1[j + 1] - t1[j - 1];
        float gy = t2[j - 1] + 2.0f * t2[j] + t2[j + 1];
        m[s] = sqrtf(gx * gx + gy * gy);   // exact sqrtf: matches numpy bitwise
    }

    // NMS (horizontal) + double threshold.
    float acc[8];
    #pragma unroll
    for (int s = 0; s < 8; ++s) {
        float mc = m[s + 1];
        bool keep = (mc >= m[s]) && (mc >= m[s + 2]);
        float e = keep ? mc : 0.0f;
        // strong -> 255; weak [0.05, 0.15] -> 0; below-low passes through
        acc[s] = (e > 0.15f) ? 255.0f : ((e >= 0.05f) ? 0.0f : e);
    }

    // Border shell of the output is exactly zero in the reference.
    if (r == 0 || r == Ht - 1) {
        #pragma unroll
        for (int s = 0; s < 8; ++s) acc[s] = 0.0f;
    }
    if (cbase == 0)           acc[0] = 0.0f;
    if (cbase + 7 == Wd - 1)  acc[7] = 0.0f;

    float4* o4 = reinterpret_cast<float4*>(out + (size_t)r * Wd + cbase);
    o4[0] = make_float4(acc[0], acc[1], acc[2], acc[3]);
    o4[1] = make_float4(acc[4], acc[5], acc[6], acc[7]);
}

extern "C" void kernel_launch(void* const* d_in, const int* in_sizes, int n_in,
                              void* d_out, int out_size, void* d_ws, size_t ws_size,
                              hipStream_t stream) {
    const float* x = (const float*)d_in[0];
    float* out = (float*)d_out;
    dim3 grid(Wd / TW, Ht / TH);
    canny_kernel<<<grid, dim3(256), 0, stream>>>(x, out);
}

// Round 4
// 114.359 us; speedup vs baseline: 1.1625x; 1.0898x over previous
//
#include <hip/hip_runtime.h>
#include <math.h>

// Canny-style Sobel NMS + double threshold on 4096x4096 f32.
// Reference's direction predicate b1 is vacuously true (radians compared to
// degree thresholds), so NMS always compares horizontal neighbors.
//
// R4 (= R3 with compile fix): no LDS, no barrier. Each thread = 1 output row
// x 8 cols; 12 independent aligned float4 global loads (3 rows x 16-col
// window), all register compute. L1/L2 absorb the 3x-vertical / 2x-horizontal
// read overlap; non-temporal stores keep the write stream from evicting halo
// lines in L2. Uses clang ext_vector_type since __builtin_nontemporal_store
// rejects HIP_vector_type<float,4>.

constexpr int Wd = 4096;
constexpr int Ht = 4096;

typedef float f4 __attribute__((ext_vector_type(4)));

__global__ __launch_bounds__(256) void canny_kernel(const float* __restrict__ x,
                                                    float* __restrict__ out) {
    const int tid   = threadIdx.x;
    const int strip = blockIdx.x * 64 + (tid & 63);   // 8-col strip index, 0..511
    const int r     = blockIdx.y * 4  + (tid >> 6);   // output row
    const int cbase = strip * 8;

    // Row clamp: border output rows are forced to 0 below, so clamped-row
    // garbage never escapes (all loaded values are finite).
    const int rm = (r == 0) ? 0 : r - 1;
    const int rp = (r == Ht - 1) ? Ht - 1 : r + 1;
    const bool left  = (cbase == 0);
    const bool right = (cbase + 8 == Wd);

    const float* xa = x + (size_t)rm * Wd + (cbase - 4);   // row r-1, window col 0
    const float* xb = x + (size_t)r  * Wd + (cbase - 4);   // row r
    const float* xc = x + (size_t)rp * Wd + (cbase - 4);   // row r+1

    // Window cols w=0..15 = image cols cbase-4+w. Chunks are 16B-aligned and
    // fully in-bounds or fully out (only chunk 0 of the left strip / chunk 3
    // of the right strip are OOB -> zero, matching the zero-pad conv).
    float ar[16], br[16], cr[16];
    const f4 z4 = {0.f, 0.f, 0.f, 0.f};
    #pragma unroll
    for (int k = 0; k < 4; ++k) {
        const bool ok = !((k == 0 && left) || (k == 3 && right));
        f4 va = ok ? *reinterpret_cast<const f4*>(xa + 4 * k) : z4;
        f4 vb = ok ? *reinterpret_cast<const f4*>(xb + 4 * k) : z4;
        f4 vc = ok ? *reinterpret_cast<const f4*>(xc + 4 * k) : z4;
        *reinterpret_cast<f4*>(&ar[4 * k]) = va;
        *reinterpret_cast<f4*>(&br[4 * k]) = vb;
        *reinterpret_cast<f4*>(&cr[4 * k]) = vc;
    }

    // Vertical pass at w = i+2 (i = 0..11): t1 = smooth (gx), t2 = diff (gy).
    float t1[12], t2[12];
    #pragma unroll
    for (int i = 0; i < 12; ++i) {
        float a = ar[i + 2], b = br[i + 2], c = cr[i + 2];
        t1[i] = a + 2.0f * b + c;
        t2[i] = a - c;
    }

    // Gradient magnitude at image col cbase-1+s (s = 0..9), w = s+3.
    float m[10];
    #pragma unroll
    for (int s = 0; s < 10; ++s) {
        float gx = t1[s + 2] - t1[s];
        float gy = t2[s] + 2.0f * t2[s + 1] + t2[s + 2];
        m[s] = sqrtf(gx * gx + gy * gy);   // exact sqrtf: matched numpy bitwise in R1/R2
    }

    // NMS (horizontal neighbors) + double threshold.
    float acc[8];
    #pragma unroll
    for (int o = 0; o < 8; ++o) {
        float mc = m[o + 1];
        bool keep = (mc >= m[o]) && (mc >= m[o + 2]);
        float e = keep ? mc : 0.0f;
        // strong -> 255; weak [0.05, 0.15] -> 0; below-low passes through
        acc[o] = (e > 0.15f) ? 255.0f : ((e >= 0.05f) ? 0.0f : e);
    }

    // Zero border shell, exactly as the reference.
    if (r == 0 || r == Ht - 1) {
        #pragma unroll
        for (int o = 0; o < 8; ++o) acc[o] = 0.0f;
    }
    if (left)  acc[0] = 0.0f;
    if (right) acc[7] = 0.0f;

    float* op = out + (size_t)r * Wd + cbase;
    f4 lo = {acc[0], acc[1], acc[2], acc[3]};
    f4 hi = {acc[4], acc[5], acc[6], acc[7]};
    __builtin_nontemporal_store(lo, reinterpret_cast<f4*>(op));
    __builtin_nontemporal_store(hi, reinterpret_cast<f4*>(op) + 1);
}

extern "C" void kernel_launch(void* const* d_in, const int* in_sizes, int n_in,
                              void* d_out, int out_size, void* d_ws, size_t ws_size,
                              hipStream_t stream) {
    const float* x = (const float*)d_in[0];
    float* out = (float*)d_out;
    dim3 grid(Wd / (64 * 8), Ht / 4);   // (8, 1024), 256 threads/block
    canny_kernel<<<grid, dim3(256), 0, stream>>>(x, out);
}